// Round 3
// baseline (593.049 us; speedup 1.0000x reference)
//
#include <hip/hip_runtime.h>
#include <math.h>

// Problem constants
#define BG   64      // graphs
#define NN   2048    // nodes per graph
#define DD   256     // hidden dim
#define CQ   16      // 12 class queries + 4 group queries fused
#define CS   64      // nodes per chunk
#define NCH  32      // 64-node chunks per graph

// Workspace layout (in floats)
static constexpr size_t WS_Q16 = 0;                                  // [16][256]
static constexpr size_t WS_H   = 4096;                               // [4][512]
static constexpr size_t WS_S   = 6144;                               // scores [64][12][2048]
static constexpr size_t WS_ML  = WS_S + (size_t)BG * 12 * NN;        // [2048][32] chunk m|l
static constexpr size_t WS_PL  = WS_ML + (size_t)BG * NCH * 32;      // pooled [2048][16][256]

// ---------------------------------------------------------------------------
// A1: h[g][j] = relu(q[g] . w1[g][:,j] + b1[g][j]); copy group queries to
// Q16 rows 12..15.  grid 64 = 4 groups x 16 j-chunks of 32, block 256.
__global__ __launch_bounds__(256) void kA1(const float* __restrict__ gq,
                                           const float* __restrict__ w1,
                                           const float* __restrict__ b1,
                                           float* __restrict__ ws) {
    int blk = blockIdx.x;
    int g   = blk >> 4;
    int jb  = (blk & 15) * 32;
    int t   = threadIdx.x;
    __shared__ float qlds[256];
    qlds[t] = gq[g * 256 + t];
    if ((blk & 15) == 0) ws[WS_Q16 + (12 + g) * 256 + t] = gq[g * 256 + t];
    __syncthreads();
    int jl = t & 31, dp = t >> 5;              // 32 j x 8 d-parts
    float acc = 0.f;
    const float* wp = w1 + ((size_t)g * 256) * 512 + jb + jl;
    #pragma unroll 8
    for (int i = 0; i < 32; ++i) {
        int d = dp * 32 + i;
        acc += qlds[d] * wp[(size_t)d * 512];
    }
    __shared__ float red[8][33];
    red[dp][jl] = acc;
    __syncthreads();
    if (dp == 0) {
        float s = 0.f;
        #pragma unroll
        for (int p = 0; p < 8; ++p) s += red[p][jl];
        s += b1[g * 512 + jb + jl];
        ws[WS_H + g * 512 + jb + jl] = fmaxf(s, 0.f);
    }
}

// A2: flat[g][k] = h[g] . w2[g][:,k] + b2[g][k] -> Q16 rows 0..11.
// grid 192 = 4 groups x 48 k-chunks of 16, block 256 (16 k x 16 d-parts).
__global__ __launch_bounds__(256) void kA2(const float* __restrict__ w2,
                                           const float* __restrict__ b2,
                                           float* __restrict__ ws) {
    int blk = blockIdx.x;
    int g   = blk / 48;
    int kb  = (blk % 48) * 16;
    int t   = threadIdx.x;
    __shared__ float hlds[512];
    hlds[t]       = ws[WS_H + g * 512 + t];
    hlds[t + 256] = ws[WS_H + g * 512 + t + 256];
    __syncthreads();
    int kl = t & 15, dp = t >> 4;              // 16 k x 16 d-parts (32 each)
    float acc = 0.f;
    const float* wp = w2 + ((size_t)g * 512) * 768 + kb + kl;
    #pragma unroll 8
    for (int i = 0; i < 32; ++i) {
        int jj = dp * 32 + i;
        acc += hlds[jj] * wp[(size_t)jj * 768];
    }
    __shared__ float red[16][17];
    red[dp][kl] = acc;
    __syncthreads();
    if (dp == 0) {
        float s = 0.f;
        #pragma unroll
        for (int p = 0; p < 16; ++p) s += red[p][kl];
        ws[WS_Q16 + g * 768 + kb + kl] = s + b2[g * 768 + kb + kl];
    }
}

// ---------------------------------------------------------------------------
// F: fused scores + chunk-softmax-partials + chunk pooling.
// grid 2048 = (b, chunk of 64 nodes); block 256 (4 waves); target 8 blocks/CU.
// Phase 1: wave = d-quarter (UNIFORM -> q fragments come in via s_load from
//          the L2-hot 16KB q table; zero LDS broadcast), lane = node.
//          Quarter partials staged in 16KB LDS, combined+scaled; class score
//          rows -> ws.
// Phase 2: per-c chunk max & sumexp (16 slots + shfl); exp-weights in red[0..1023].
// Phase 3: wave owns 4 queries x all 64 nodes (NO cross-wave combine);
//          lane owns float4 of D; ev reads are wave-uniform LDS broadcasts;
//          x re-read is L2-hot; direct pooled-partial writes.
__global__ __launch_bounds__(256, 6) void kF(const float* __restrict__ x,
                                             const float* __restrict__ q16,
                                             float* __restrict__ ws) {
    __shared__ float red[4 * 16 * 64];         // 16 KB; red[0..1023] = weights
    __shared__ float mbuf[16];

    int t    = threadIdx.x;
    int blk  = blockIdx.x;
    int b    = blk >> 5, ch = blk & 31;
    int gn0  = b * NN + ch * CS;               // global node base of this chunk

    int lane = t & 63;
    int wave = t >> 6;
    // wave-uniform d-quarter base (floats); readfirstlane => scalar loads
    int qoff = __builtin_amdgcn_readfirstlane(wave * 64);

    // ---- Phase 1: partial scores; thread = (node=lane, d-quarter=wave) ----
    const float4* xa = (const float4*)x + (size_t)(gn0 + lane) * 64 + wave * 16;
    const float*  qb = q16 + qoff;             // + c*256 + i*4, uniform
    float sc[16];
    #pragma unroll
    for (int c = 0; c < 16; ++c) sc[c] = 0.f;

    #pragma unroll 4
    for (int i = 0; i < 16; ++i) {
        float4 xi = xa[i];
        #pragma unroll
        for (int c = 0; c < 16; ++c) {
            float4 q4 = *(const float4*)(qb + c * 256 + i * 4);
            sc[c] += q4.x * xi.x + q4.y * xi.y + q4.z * xi.z + q4.w * xi.w;
        }
    }

    // stage quarter partials: red[wave][c][node]
    #pragma unroll
    for (int c = 0; c < 16; ++c) red[wave * 1024 + c * 64 + lane] = sc[c];
    __syncthreads();

    // combine quarters + scale; weights live in red[0..1023]; scores -> ws
    {
        float* srow = ws + WS_S + (size_t)b * 12 * NN + ch * CS;
        #pragma unroll
        for (int k = 0; k < 4; ++k) {
            int o = k * 256 + t;               // o = c*64 + node
            float s = (red[o] + red[o + 1024] + red[o + 2048] + red[o + 3072])
                      * 0.0625f;
            red[o] = s;
            int c = o >> 6;
            if (c < 12) srow[(size_t)c * NN + (o & 63)] = s;
        }
    }
    __syncthreads();

    // ---- Phase 2: chunk max / sumexp per c ----
    {
        int c = t >> 4, slot = t & 15;         // 16 c x 16 slots, 4 nodes each
        float mv = -1e30f;
        #pragma unroll
        for (int k = 0; k < 4; ++k) mv = fmaxf(mv, red[c * 64 + slot + k * 16]);
        #pragma unroll
        for (int off = 1; off < 16; off <<= 1) mv = fmaxf(mv, __shfl_xor(mv, off, 64));
        if (slot == 0) {
            mbuf[c] = mv;
            ws[WS_ML + (size_t)blk * 32 + c] = mv;
        }
    }
    __syncthreads();
    #pragma unroll
    for (int k = 0; k < 4; ++k) {
        int o = k * 256 + t;
        red[o] = __expf(red[o] - mbuf[o >> 6]);
    }
    __syncthreads();
    {
        int c = t >> 4, slot = t & 15;
        float lv = 0.f;
        #pragma unroll
        for (int k = 0; k < 4; ++k) lv += red[c * 64 + slot + k * 16];
        #pragma unroll
        for (int off = 1; off < 16; off <<= 1) lv += __shfl_xor(lv, off, 64);
        if (slot == 0) ws[WS_ML + (size_t)blk * 32 + 16 + c] = lv;
    }
    // no barrier: phase 3 only READS red[0..1023], final after the exp barrier

    // ---- Phase 3: pooling; wave owns 4 query rows x all 64 nodes ----
    int c0 = wave * 4;
    float4 acc[4];
    #pragma unroll
    for (int j = 0; j < 4; ++j) acc[j] = make_float4(0.f, 0.f, 0.f, 0.f);

    const float4* xq = (const float4*)x + (size_t)gn0 * 64 + lane;
    for (int nq = 0; nq < 16; ++nq) {          // node quads over 64 nodes
        float4 x0 = xq[(size_t)(nq * 4 + 0) * 64];
        float4 x1 = xq[(size_t)(nq * 4 + 1) * 64];
        float4 x2 = xq[(size_t)(nq * 4 + 2) * 64];
        float4 x3 = xq[(size_t)(nq * 4 + 3) * 64];
        #pragma unroll
        for (int j = 0; j < 4; ++j) {
            float4 ev = *(const float4*)&red[(c0 + j) * 64 + nq * 4];
            acc[j].x += ev.x * x0.x + ev.y * x1.x + ev.z * x2.x + ev.w * x3.x;
            acc[j].y += ev.x * x0.y + ev.y * x1.y + ev.z * x2.y + ev.w * x3.y;
            acc[j].z += ev.x * x0.z + ev.y * x1.z + ev.z * x2.z + ev.w * x3.z;
            acc[j].w += ev.x * x0.w + ev.y * x1.w + ev.z * x2.w + ev.w * x3.w;
        }
    }

    float4* po = (float4*)(ws + WS_PL + (size_t)blk * (CQ * 256));
    #pragma unroll
    for (int j = 0; j < 4; ++j) po[(c0 + j) * 64 + lane] = acc[j];
}

// ---------------------------------------------------------------------------
// E: combine 32 chunk partials (m,l,pooled) -> pooled row; LN; MLP -> logits;
// for c<12 also writes the attn12 output row.  grid 1024, block 256.
__global__ __launch_bounds__(256) void kE(float* __restrict__ ws,
        const float* __restrict__ lnG12, const float* __restrict__ lnB12,
        const float* __restrict__ wA12,  const float* __restrict__ bA12,
        const float* __restrict__ wB12,  const float* __restrict__ bB12,
        const float* __restrict__ lnG4,  const float* __restrict__ lnB4,
        const float* __restrict__ wA4,   const float* __restrict__ bA4,
        const float* __restrict__ wB4,   const float* __restrict__ bB4,
        float* __restrict__ out) {
    int bc = blockIdx.x;
    int b = bc >> 4, c = bc & 15;
    int t = threadIdx.x, wave = t >> 6, lane = t & 63;

    __shared__ float scl[NCH];
    __shared__ float sinvl, smv;
    if (t < NCH) {                             // 32 lanes of wave 0
        float mi = ws[WS_ML + (size_t)(b * NCH + t) * 32 + c];
        float li = ws[WS_ML + (size_t)(b * NCH + t) * 32 + 16 + c];
        float m = mi;
        #pragma unroll
        for (int off = 1; off < 32; off <<= 1) m = fmaxf(m, __shfl_xor(m, off, 64));
        float e = __expf(mi - m);
        float pl = e * li;
        #pragma unroll
        for (int off = 1; off < 32; off <<= 1) pl += __shfl_xor(pl, off, 64);
        scl[t] = e;
        if (t == 0) {
            sinvl = 1.f / pl;
            smv   = m;
        }
    }
    __syncthreads();

    float v = 0.f;
    for (int i = 0; i < NCH; ++i)
        v += scl[i] * ws[WS_PL + ((size_t)(b * NCH + i) * CQ + c) * 256 + t];
    v *= sinvl;

    // attn12 output (independent of the MLP below; overlaps its latency)
    if (c < 12) {
        float m  = smv;
        float il = sinvl;
        const float4* sr = (const float4*)(ws + WS_S + ((size_t)b * 12 + c) * NN);
        float4* ar = (float4*)(out + 1024) + ((size_t)b * 12 + c) * (NN / 4);
        #pragma unroll
        for (int k = 0; k < 2; ++k) {
            float4 s4 = sr[t + k * 256];
            float4 e4;
            e4.x = __expf(s4.x - m) * il;
            e4.y = __expf(s4.y - m) * il;
            e4.z = __expf(s4.z - m) * il;
            e4.w = __expf(s4.w - m) * il;
            ar[t + k * 256] = e4;
        }
    }

    __shared__ float wr1[4], wr2[4];
    float s = v;
    #pragma unroll
    for (int off = 32; off; off >>= 1) s += __shfl_xor(s, off, 64);
    if (lane == 0) wr1[wave] = s;
    __syncthreads();
    float mu = (wr1[0] + wr1[1] + wr1[2] + wr1[3]) * (1.f / 256.f);
    float dv = v - mu;
    s = dv * dv;
    #pragma unroll
    for (int off = 32; off; off >>= 1) s += __shfl_xor(s, off, 64);
    if (lane == 0) wr2[wave] = s;
    __syncthreads();
    float var = (wr2[0] + wr2[1] + wr2[2] + wr2[3]) * (1.f / 256.f);

    bool is12 = (c < 12);
    const float* lg = is12 ? lnG12 : lnG4;
    const float* lb = is12 ? lnB12 : lnB4;
    const float* wA = is12 ? wA12  : wA4;
    const float* bA = is12 ? bA12  : bA4;
    const float* wB = is12 ? wB12  : wB4;
    const float* bB = is12 ? bB12  : bB4;

    __shared__ float ylds[256];
    __shared__ float hred[256];
    __shared__ float hlds[128];
    float y = dv * rsqrtf(var + 1e-5f) * lg[t] + lb[t];
    ylds[t] = y;
    __syncthreads();
    {
        int j = t & 127, half = t >> 7;
        float hh = 0.f;
        const float* wc = wA + (size_t)half * 128 * 128 + j;
        #pragma unroll 4
        for (int d = 0; d < 128; ++d) hh += ylds[half * 128 + d] * wc[(size_t)d * 128];
        hred[t] = hh;
    }
    __syncthreads();
    if (t < 128) hlds[t] = fmaxf(hred[t] + hred[t + 128] + bA[t], 0.f);
    __syncthreads();
    if (t < 64) {
        float pp = hlds[t] * wB[t] + hlds[t + 64] * wB[t + 64];
        #pragma unroll
        for (int off = 32; off; off >>= 1) pp += __shfl_xor(pp, off, 64);
        if (t == 0) {
            float logit = pp + bB[0];
            if (is12) out[b * 12 + c] = logit;
            else      out[768 + b * 4 + (c - 12)] = logit;
        }
    }
}

// ---------------------------------------------------------------------------
extern "C" void kernel_launch(void* const* d_in, const int* in_sizes, int n_in,
                              void* d_out, int out_size, void* d_ws, size_t ws_size,
                              hipStream_t stream) {
    const float* x     = (const float*)d_in[0];   // [131072, 256]
    const float* gq    = (const float*)d_in[2];   // [4, 256]
    const float* w1    = (const float*)d_in[3];   // [4, 256, 512]
    const float* b1    = (const float*)d_in[4];   // [4, 512]
    const float* w2    = (const float*)d_in[5];   // [4, 512, 768]
    const float* b2    = (const float*)d_in[6];   // [4, 768]
    const float* ln12g = (const float*)d_in[7];
    const float* ln12b = (const float*)d_in[8];
    const float* w12a  = (const float*)d_in[9];   // [256, 128]
    const float* b12a  = (const float*)d_in[10];
    const float* w12b  = (const float*)d_in[11];  // [128, 1]
    const float* b12b  = (const float*)d_in[12];
    const float* ln4g  = (const float*)d_in[13];
    const float* ln4b  = (const float*)d_in[14];
    const float* w4a   = (const float*)d_in[15];
    const float* b4a   = (const float*)d_in[16];
    const float* w4b   = (const float*)d_in[17];
    const float* b4b   = (const float*)d_in[18];

    float* out = (float*)d_out;               // [768 logits12][256 logits4][1572864 attn12]
    float* ws  = (float*)d_ws;

    kA1<<<64,       256, 0, stream>>>(gq, w1, b1, ws);
    kA2<<<192,      256, 0, stream>>>(w2, b2, ws);
    kF <<<BG * NCH, 256, 0, stream>>>(x, ws + WS_Q16, ws);
    kE <<<1024,     256, 0, stream>>>(ws,
            ln12g, ln12b, w12a, b12a, w12b, b12b,
            ln4g,  ln4b,  w4a,  b4a,  w4b,  b4b, out);
}

// Round 4
// 327.362 us; speedup vs baseline: 1.8116x; 1.8116x over previous
//
#include <hip/hip_runtime.h>
#include <math.h>

// Problem constants
#define BG   64      // graphs
#define NN   2048    // nodes per graph
#define DD   256     // hidden dim
#define CQ   16      // 12 class queries + 4 group queries fused
#define CS   128     // nodes per chunk
#define NCH  16      // 128-node chunks per graph

// Workspace layout (in floats) -- round-1 proven layout
static constexpr size_t WS_Q16 = 0;                                  // [16][256]
static constexpr size_t WS_H   = 4096;                               // [4][512]
static constexpr size_t WS_S   = 6144;                               // scores [64][12][2048]
static constexpr size_t WS_ML  = WS_S + (size_t)BG * 12 * NN;        // [64*16][32] chunk m|l
static constexpr size_t WS_PL  = WS_ML + (size_t)BG * NCH * 32;      // pooled [64*16][16][256]

// ---------------------------------------------------------------------------
// A1: h[g][j] = relu(q[g] . w1[g][:,j] + b1[g][j]); copy group queries to
// Q16 rows 12..15.  grid 64 = 4 groups x 16 j-chunks of 32, block 256.
__global__ __launch_bounds__(256) void kA1(const float* __restrict__ gq,
                                           const float* __restrict__ w1,
                                           const float* __restrict__ b1,
                                           float* __restrict__ ws) {
    int blk = blockIdx.x;
    int g   = blk >> 4;
    int jb  = (blk & 15) * 32;
    int t   = threadIdx.x;
    __shared__ float qlds[256];
    qlds[t] = gq[g * 256 + t];
    if ((blk & 15) == 0) ws[WS_Q16 + (12 + g) * 256 + t] = gq[g * 256 + t];
    __syncthreads();
    int jl = t & 31, dp = t >> 5;              // 32 j x 8 d-parts
    float acc = 0.f;
    const float* wp = w1 + ((size_t)g * 256) * 512 + jb + jl;
    #pragma unroll 8
    for (int i = 0; i < 32; ++i) {
        int d = dp * 32 + i;
        acc += qlds[d] * wp[(size_t)d * 512];
    }
    __shared__ float red[8][33];
    red[dp][jl] = acc;
    __syncthreads();
    if (dp == 0) {
        float s = 0.f;
        #pragma unroll
        for (int p = 0; p < 8; ++p) s += red[p][jl];
        s += b1[g * 512 + jb + jl];
        ws[WS_H + g * 512 + jb + jl] = fmaxf(s, 0.f);
    }
}

// A2: flat[g][k] = h[g] . w2[g][:,k] + b2[g][k] -> Q16 rows 0..11.
// grid 192 = 4 groups x 48 k-chunks of 16, block 256 (16 k x 16 d-parts).
__global__ __launch_bounds__(256) void kA2(const float* __restrict__ w2,
                                           const float* __restrict__ b2,
                                           float* __restrict__ ws) {
    int blk = blockIdx.x;
    int g   = blk / 48;
    int kb  = (blk % 48) * 16;
    int t   = threadIdx.x;
    __shared__ float hlds[512];
    hlds[t]       = ws[WS_H + g * 512 + t];
    hlds[t + 256] = ws[WS_H + g * 512 + t + 256];
    __syncthreads();
    int kl = t & 15, dp = t >> 4;              // 16 k x 16 d-parts (32 each)
    float acc = 0.f;
    const float* wp = w2 + ((size_t)g * 512) * 768 + kb + kl;
    #pragma unroll 8
    for (int i = 0; i < 32; ++i) {
        int jj = dp * 32 + i;
        acc += hlds[jj] * wp[(size_t)jj * 768];
    }
    __shared__ float red[16][17];
    red[dp][kl] = acc;
    __syncthreads();
    if (dp == 0) {
        float s = 0.f;
        #pragma unroll
        for (int p = 0; p < 16; ++p) s += red[p][kl];
        ws[WS_Q16 + g * 768 + kb + kl] = s + b2[g * 768 + kb + kl];
    }
}

// ---------------------------------------------------------------------------
// F: fused scores + chunk-softmax-partials + chunk pooling, split by
// query-half.  grid 2048; block 256 (4 waves).
// Block mapping is XCD-aware: consecutive blockIdx round-robin over 8 XCDs,
// so the two query-half blocks of a chunk are placed 8 dispatch-IDs apart
// (same XCD) -> the second block's x reads hit that XCD's L2.
//   half = (blk>>3)&1,  lin = (blk&7)|((blk>>4)<<3),  b = lin>>4, ch = lin&15
// NO min-waves launch bound: rounds 2/3 proved the register cap causes
// catastrophic scratch spill.  Register footprint is kept <=64 by design
// (sc[8] phase 1, 2x float4 acc phase 3) so 8 blocks/CU happens naturally.
__global__ __launch_bounds__(256) void kF(const float* __restrict__ x,
                                          float* __restrict__ ws) {
    __shared__ float4 qlds[8 * 64];            // 8 KB: this block's 8 query rows
    __shared__ float  wlds[8 * CS];            // 4 KB: scores then exp-weights
    __shared__ float  mbuf[8];

    int t     = threadIdx.x;
    int blk   = blockIdx.x;
    int chalf = (blk >> 3) & 1;                // query-half: rows chalf*8..+7
    int lin   = (blk & 7) | ((blk >> 4) << 3); // [0,1024)
    int b     = lin >> 4, ch = lin & 15;
    int gn0   = b * NN + ch * CS;              // global node base of this chunk

    const float4* qg = (const float4*)(ws + WS_Q16) + (size_t)chalf * 8 * 64;
    qlds[t]       = qg[t];
    qlds[t + 256] = qg[t + 256];
    __syncthreads();

    // ---- Phase 1: scores; thread = (node = t&127, d-half = t>>7) ----
    int node = t & 127, half = t >> 7;
    const float4* xa = (const float4*)x + (size_t)(gn0 + node) * 64 + half * 32;
    float sc[8];
    #pragma unroll
    for (int c = 0; c < 8; ++c) sc[c] = 0.f;

    #pragma unroll 4
    for (int i = 0; i < 32; ++i) {
        float4 xi = xa[i];
        #pragma unroll
        for (int c = 0; c < 8; ++c) {
            float4 q = qlds[c * 64 + half * 32 + i];
            sc[c] += q.x * xi.x + q.y * xi.y + q.z * xi.z + q.w * xi.w;
        }
    }

    // combine d-halves through wlds; half0 finishes with scale
    if (half == 1) {
        #pragma unroll
        for (int c = 0; c < 8; ++c) wlds[c * CS + node] = sc[c];
    }
    __syncthreads();
    if (half == 0) {
        #pragma unroll
        for (int c = 0; c < 8; ++c)
            wlds[c * CS + node] = (sc[c] + wlds[c * CS + node]) * 0.0625f;
    }
    __syncthreads();

    // scaled scores for class queries (global c < 12) -> ws
    {
        float* srow = ws + WS_S + (size_t)b * 12 * NN + ch * CS;
        #pragma unroll
        for (int k = 0; k < 4; ++k) {          // 8*128 = 1024 = 4*256
            int idx = k * 256 + t;
            int cl  = idx >> 7, nn = idx & 127;
            int gc  = chalf * 8 + cl;
            if (gc < 12) srow[(size_t)gc * NN + nn] = wlds[idx];
        }
    }

    // ---- Phase 2: chunk max / sumexp per c ----
    {
        int cl = t >> 5, slot = t & 31;        // 8 c x 32 slots
        float mv = -1e30f;
        #pragma unroll
        for (int k = 0; k < 4; ++k) mv = fmaxf(mv, wlds[cl * CS + slot + k * 32]);
        #pragma unroll
        for (int off = 1; off < 32; off <<= 1) mv = fmaxf(mv, __shfl_xor(mv, off, 64));
        if (slot == 0) mbuf[cl] = mv;
    }
    __syncthreads();
    #pragma unroll
    for (int k = 0; k < 4; ++k) {              // 8*128 = 1024 = 4*256
        int idx = k * 256 + t;
        wlds[idx] = __expf(wlds[idx] - mbuf[idx >> 7]);
    }
    __syncthreads();
    {
        int cl = t >> 5, slot = t & 31;
        float lv = 0.f;
        #pragma unroll
        for (int k = 0; k < 4; ++k) lv += wlds[cl * CS + slot + k * 32];
        #pragma unroll
        for (int off = 1; off < 32; off <<= 1) lv += __shfl_xor(lv, off, 64);
        if (slot == 0) {
            size_t mlb = WS_ML + (size_t)(b * NCH + ch) * 32 + chalf * 8 + cl;
            ws[mlb]      = mbuf[cl];
            ws[mlb + 16] = lv;
        }
    }
    // wlds stable from here on (sum only read it) -- no extra barrier needed

    // ---- Phase 3: pooling; wave owns 2 query rows x all 128 nodes ----
    int wave = t >> 6, lane = t & 63;
    float4 acc0 = make_float4(0.f, 0.f, 0.f, 0.f);
    float4 acc1 = make_float4(0.f, 0.f, 0.f, 0.f);
    int c0 = wave * 2;                         // local query rows c0, c0+1

    const float4* xq = (const float4*)x + (size_t)gn0 * 64 + lane;
    for (int nq = 0; nq < 32; ++nq) {          // node quads over 128 nodes
        float4 x0 = xq[(size_t)(nq * 4 + 0) * 64];
        float4 x1 = xq[(size_t)(nq * 4 + 1) * 64];
        float4 x2 = xq[(size_t)(nq * 4 + 2) * 64];
        float4 x3 = xq[(size_t)(nq * 4 + 3) * 64];
        float4 e0 = *(const float4*)&wlds[c0 * CS + nq * 4];
        float4 e1 = *(const float4*)&wlds[(c0 + 1) * CS + nq * 4];
        acc0.x += e0.x * x0.x + e0.y * x1.x + e0.z * x2.x + e0.w * x3.x;
        acc0.y += e0.x * x0.y + e0.y * x1.y + e0.z * x2.y + e0.w * x3.y;
        acc0.z += e0.x * x0.z + e0.y * x1.z + e0.z * x2.z + e0.w * x3.z;
        acc0.w += e0.x * x0.w + e0.y * x1.w + e0.z * x2.w + e0.w * x3.w;
        acc1.x += e1.x * x0.x + e1.y * x1.x + e1.z * x2.x + e1.w * x3.x;
        acc1.y += e1.x * x0.y + e1.y * x1.y + e1.z * x2.y + e1.w * x3.y;
        acc1.z += e1.x * x0.z + e1.y * x1.z + e1.z * x2.z + e1.w * x3.z;
        acc1.w += e1.x * x0.w + e1.y * x1.w + e1.z * x2.w + e1.w * x3.w;
    }

    // direct pooled-partial writes (no cross-wave combine needed)
    float4* po = (float4*)(ws + WS_PL + (size_t)(b * NCH + ch) * (CQ * 256));
    po[(chalf * 8 + c0) * 64 + lane]     = acc0;
    po[(chalf * 8 + c0 + 1) * 64 + lane] = acc1;
}

// ---------------------------------------------------------------------------
// E: combine 16 chunk partials (m,l,pooled) -> pooled row; LN; MLP -> logits;
// for c<12 also writes the attn12 output row.  grid 1024, block 256.
__global__ __launch_bounds__(256) void kE(float* __restrict__ ws,
        const float* __restrict__ lnG12, const float* __restrict__ lnB12,
        const float* __restrict__ wA12,  const float* __restrict__ bA12,
        const float* __restrict__ wB12,  const float* __restrict__ bB12,
        const float* __restrict__ lnG4,  const float* __restrict__ lnB4,
        const float* __restrict__ wA4,   const float* __restrict__ bA4,
        const float* __restrict__ wB4,   const float* __restrict__ bB4,
        float* __restrict__ out) {
    int bc = blockIdx.x;
    int b = bc >> 4, c = bc & 15;
    int t = threadIdx.x, wave = t >> 6, lane = t & 63;

    __shared__ float scl[NCH];
    __shared__ float sinvl, smv;
    if (t < NCH) {                             // 16 lanes of wave 0
        float mi = ws[WS_ML + (size_t)(b * NCH + t) * 32 + c];
        float li = ws[WS_ML + (size_t)(b * NCH + t) * 32 + 16 + c];
        float m = mi;
        #pragma unroll
        for (int off = 1; off < 16; off <<= 1) m = fmaxf(m, __shfl_xor(m, off, 64));
        float e = __expf(mi - m);
        float pl = e * li;
        #pragma unroll
        for (int off = 1; off < 16; off <<= 1) pl += __shfl_xor(pl, off, 64);
        scl[t] = e;
        if (t == 0) {
            sinvl = 1.f / pl;
            smv   = m;
        }
    }
    __syncthreads();

    float v = 0.f;
    for (int i = 0; i < NCH; ++i)
        v += scl[i] * ws[WS_PL + ((size_t)(b * NCH + i) * CQ + c) * 256 + t];
    v *= sinvl;

    // attn12 output (independent of the MLP below; overlaps its latency)
    if (c < 12) {
        float m  = smv;
        float il = sinvl;
        const float4* sr = (const float4*)(ws + WS_S + ((size_t)b * 12 + c) * NN);
        float4* ar = (float4*)(out + 1024) + ((size_t)b * 12 + c) * (NN / 4);
        #pragma unroll
        for (int k = 0; k < 2; ++k) {
            float4 s4 = sr[t + k * 256];
            float4 e4;
            e4.x = __expf(s4.x - m) * il;
            e4.y = __expf(s4.y - m) * il;
            e4.z = __expf(s4.z - m) * il;
            e4.w = __expf(s4.w - m) * il;
            ar[t + k * 256] = e4;
        }
    }

    __shared__ float wr1[4], wr2[4];
    float s = v;
    #pragma unroll
    for (int off = 32; off; off >>= 1) s += __shfl_xor(s, off, 64);
    if (lane == 0) wr1[wave] = s;
    __syncthreads();
    float mu = (wr1[0] + wr1[1] + wr1[2] + wr1[3]) * (1.f / 256.f);
    float dv = v - mu;
    s = dv * dv;
    #pragma unroll
    for (int off = 32; off; off >>= 1) s += __shfl_xor(s, off, 64);
    if (lane == 0) wr2[wave] = s;
    __syncthreads();
    float var = (wr2[0] + wr2[1] + wr2[2] + wr2[3]) * (1.f / 256.f);

    bool is12 = (c < 12);
    const float* lg = is12 ? lnG12 : lnG4;
    const float* lb = is12 ? lnB12 : lnB4;
    const float* wA = is12 ? wA12  : wA4;
    const float* bA = is12 ? bA12  : bA4;
    const float* wB = is12 ? wB12  : wB4;
    const float* bB = is12 ? bB12  : bB4;

    __shared__ float ylds[256];
    __shared__ float hred[256];
    __shared__ float hlds[128];
    float y = dv * rsqrtf(var + 1e-5f) * lg[t] + lb[t];
    ylds[t] = y;
    __syncthreads();
    {
        int j = t & 127, half = t >> 7;
        float hh = 0.f;
        const float* wc = wA + (size_t)half * 128 * 128 + j;
        #pragma unroll 4
        for (int d = 0; d < 128; ++d) hh += ylds[half * 128 + d] * wc[(size_t)d * 128];
        hred[t] = hh;
    }
    __syncthreads();
    if (t < 128) hlds[t] = fmaxf(hred[t] + hred[t + 128] + bA[t], 0.f);
    __syncthreads();
    if (t < 64) {
        float pp = hlds[t] * wB[t] + hlds[t + 64] * wB[t + 64];
        #pragma unroll
        for (int off = 32; off; off >>= 1) pp += __shfl_xor(pp, off, 64);
        if (t == 0) {
            float logit = pp + bB[0];
            if (is12) out[b * 12 + c] = logit;
            else      out[768 + b * 4 + (c - 12)] = logit;
        }
    }
}

// ---------------------------------------------------------------------------
extern "C" void kernel_launch(void* const* d_in, const int* in_sizes, int n_in,
                              void* d_out, int out_size, void* d_ws, size_t ws_size,
                              hipStream_t stream) {
    const float* x     = (const float*)d_in[0];   // [131072, 256]
    const float* gq    = (const float*)d_in[2];   // [4, 256]
    const float* w1    = (const float*)d_in[3];   // [4, 256, 512]
    const float* b1    = (const float*)d_in[4];   // [4, 512]
    const float* w2    = (const float*)d_in[5];   // [4, 512, 768]
    const float* b2    = (const float*)d_in[6];   // [4, 768]
    const float* ln12g = (const float*)d_in[7];
    const float* ln12b = (const float*)d_in[8];
    const float* w12a  = (const float*)d_in[9];   // [256, 128]
    const float* b12a  = (const float*)d_in[10];
    const float* w12b  = (const float*)d_in[11];  // [128, 1]
    const float* b12b  = (const float*)d_in[12];
    const float* ln4g  = (const float*)d_in[13];
    const float* ln4b  = (const float*)d_in[14];
    const float* w4a   = (const float*)d_in[15];
    const float* b4a   = (const float*)d_in[16];
    const float* w4b   = (const float*)d_in[17];
    const float* b4b   = (const float*)d_in[18];

    float* out = (float*)d_out;               // [768 logits12][256 logits4][1572864 attn12]
    float* ws  = (float*)d_ws;

    kA1<<<64,         256, 0, stream>>>(gq, w1, b1, ws);
    kA2<<<192,        256, 0, stream>>>(w2, b2, ws);
    kF <<<BG*NCH*2,   256, 0, stream>>>(x, ws);
    kE <<<1024,       256, 0, stream>>>(ws,
            ln12g, ln12b, w12a, b12a, w12b, b12b,
            ln4g,  ln4b,  w4a,  b4a,  w4b,  b4b, out);
}

// Round 5
// 324.430 us; speedup vs baseline: 1.8280x; 1.0090x over previous
//
#include <hip/hip_runtime.h>
#include <math.h>

// Problem constants
#define BG   64      // graphs
#define NN   2048    // nodes per graph
#define DD   256     // hidden dim
#define CQ   16      // 12 class queries + 4 group queries fused
#define CS   64      // nodes per chunk (block)
#define SUB  16      // nodes per sub-chunk (online-softmax step)
#define NCH  32      // chunks per graph

// Workspace layout (in floats) -- 40.1 MB total, same footprint as the
// round-2/3 runs which passed (so ws_size accommodates it).
static constexpr size_t WS_Q16 = 0;                                  // [16][256]
static constexpr size_t WS_H   = 4096;                               // [4][512]
static constexpr size_t WS_S   = 6144;                               // scores [64][12][2048]
static constexpr size_t WS_ML  = WS_S + (size_t)BG * 12 * NN;        // [2048][32] chunk m|l
static constexpr size_t WS_PL  = WS_ML + (size_t)BG * NCH * 32;      // pooled [2048][16][256]

// ---------------------------------------------------------------------------
// A1: h[g][j] = relu(q[g] . w1[g][:,j] + b1[g][j]); copy group queries to
// Q16 rows 12..15.  grid 64 = 4 groups x 16 j-chunks of 32, block 256.
__global__ __launch_bounds__(256) void kA1(const float* __restrict__ gq,
                                           const float* __restrict__ w1,
                                           const float* __restrict__ b1,
                                           float* __restrict__ ws) {
    int blk = blockIdx.x;
    int g   = blk >> 4;
    int jb  = (blk & 15) * 32;
    int t   = threadIdx.x;
    __shared__ float qlds[256];
    qlds[t] = gq[g * 256 + t];
    if ((blk & 15) == 0) ws[WS_Q16 + (12 + g) * 256 + t] = gq[g * 256 + t];
    __syncthreads();
    int jl = t & 31, dp = t >> 5;              // 32 j x 8 d-parts
    float acc = 0.f;
    const float* wp = w1 + ((size_t)g * 256) * 512 + jb + jl;
    #pragma unroll 8
    for (int i = 0; i < 32; ++i) {
        int d = dp * 32 + i;
        acc += qlds[d] * wp[(size_t)d * 512];
    }
    __shared__ float red[8][33];
    red[dp][jl] = acc;
    __syncthreads();
    if (dp == 0) {
        float s = 0.f;
        #pragma unroll
        for (int p = 0; p < 8; ++p) s += red[p][jl];
        s += b1[g * 512 + jb + jl];
        ws[WS_H + g * 512 + jb + jl] = fmaxf(s, 0.f);
    }
}

// A2: flat[g][k] = h[g] . w2[g][:,k] + b2[g][k] -> Q16 rows 0..11.
// grid 192 = 4 groups x 48 k-chunks of 16, block 256 (16 k x 16 d-parts).
__global__ __launch_bounds__(256) void kA2(const float* __restrict__ w2,
                                           const float* __restrict__ b2,
                                           float* __restrict__ ws) {
    int blk = blockIdx.x;
    int g   = blk / 48;
    int kb  = (blk % 48) * 16;
    int t   = threadIdx.x;
    __shared__ float hlds[512];
    hlds[t]       = ws[WS_H + g * 512 + t];
    hlds[t + 256] = ws[WS_H + g * 512 + t + 256];
    __syncthreads();
    int kl = t & 15, dp = t >> 4;              // 16 k x 16 d-parts (32 each)
    float acc = 0.f;
    const float* wp = w2 + ((size_t)g * 512) * 768 + kb + kl;
    #pragma unroll 8
    for (int i = 0; i < 32; ++i) {
        int jj = dp * 32 + i;
        acc += hlds[jj] * wp[(size_t)jj * 768];
    }
    __shared__ float red[16][17];
    red[dp][kl] = acc;
    __syncthreads();
    if (dp == 0) {
        float s = 0.f;
        #pragma unroll
        for (int p = 0; p < 16; ++p) s += red[p][kl];
        ws[WS_Q16 + g * 768 + kb + kl] = s + b2[g * 768 + kb + kl];
    }
}

// ---------------------------------------------------------------------------
// F: single-pass streaming chunk kernel with ONLINE softmax.
// grid 2048 = (b, 64-node chunk); block 256 (4 waves); NO min-waves bound
// (rounds 2/3: a forced register cap causes catastrophic scratch spill).
//
// Per 16-node sub-chunk (4 per block):
//   1. scores from registers: thread = (node = t>>4, d-slice = t&15), x was
//      prefetched (4 float4/thread, coalesced 256B segments); q from LDS
//      (2-way-conflict-free broadcast pattern).
//   2. prefetch next sub's x into registers (overlaps softmax+pool, T14).
//   3. 16-lane shfl butterfly -> full scores; cndmask select (NO runtime
//      array index -> no scratch) -> wlds[c][n].
//   4. online softmax: running (m,l) per c in registers of the (c = t>>4)
//      group; rescale factor -> sbuf; raw score rows (c<12) -> ws.
//   5. pool: wave owns 4 queries, lane owns float4 of D; x sub re-read from
//      global -- the 16 KB sub is L2-hot (read by phase 1 ~2 barriers ago;
//      resident set ~3 MB/XCD < 4 MB L2).  acc rescaled by sbuf each sub.
// Emits (m,l) + unnormalized pooled[16][256] per chunk (flash-combine in kE).
__global__ __launch_bounds__(256) void kF(const float* __restrict__ x,
                                          float* __restrict__ ws) {
    __shared__ float qlds[CQ * 256];           // 16 KB [c][d]
    __shared__ float wlds[CQ * SUB];           // 1 KB  [c][n] scores then weights
    __shared__ float sbuf[CQ];                 // per-c rescale factor

    int t   = threadIdx.x;
    int blk = blockIdx.x;
    int b   = blk >> 5, ch = blk & 31;
    int gn0 = b * NN + ch * CS;                // global node base of this chunk

    // load q table (16 KB, L2-hot)
    {
        const float4* qg = (const float4*)(ws + WS_Q16);
        float4* ql = (float4*)qlds;
        #pragma unroll
        for (int i = 0; i < 4; ++i) ql[t + i * 256] = qg[t + i * 256];
    }

    int node = t >> 4, dp = t & 15;            // phase-1 / softmax roles
    int wave = t >> 6, lane = t & 63;          // pool roles

    float m_run = -1e30f, l_run = 0.f;         // per-c running state (c = node)
    float4 acc[4];
    #pragma unroll
    for (int j = 0; j < 4; ++j) acc[j] = make_float4(0.f, 0.f, 0.f, 0.f);

    const float4* xg = (const float4*)x + (size_t)gn0 * 64;

    // prefetch sub 0: thread covers node (t>>4), f4-dims {dp + 16i}
    float4 xr[4];
    #pragma unroll
    for (int i = 0; i < 4; ++i) xr[i] = xg[(size_t)node * 64 + dp + 16 * i];
    __syncthreads();                           // qlds ready

    for (int s = 0; s < 4; ++s) {
        // ---- scores from registers ----
        float sc[16];
        #pragma unroll
        for (int c = 0; c < 16; ++c) sc[c] = 0.f;
        #pragma unroll
        for (int i = 0; i < 4; ++i) {
            float4 xi = xr[i];
            const float4* qp = (const float4*)qlds + dp + 16 * i;
            #pragma unroll
            for (int c = 0; c < 16; ++c) {
                float4 q = qp[c * 64];
                sc[c] += q.x * xi.x + q.y * xi.y + q.z * xi.z + q.w * xi.w;
            }
        }
        // prefetch next sub (in flight across softmax + pool)
        if (s < 3) {
            #pragma unroll
            for (int i = 0; i < 4; ++i)
                xr[i] = xg[(size_t)(s + 1) * 1024 + (size_t)node * 64 + dp + 16 * i];
        }
        // butterfly over the 16 d-slice lanes -> all lanes hold full sums
        #pragma unroll
        for (int c = 0; c < 16; ++c) {
            #pragma unroll
            for (int off = 1; off < 16; off <<= 1)
                sc[c] += __shfl_xor(sc[c], off, 64);
        }
        // lane dp publishes c = dp (static-index select, rule #20)
        {
            float myv = 0.f;
            #pragma unroll
            for (int c = 0; c < 16; ++c) myv = (dp == c) ? sc[c] : myv;
            wlds[dp * SUB + node] = myv * 0.0625f;
        }
        __syncthreads();

        // ---- online softmax: thread = (c = t>>4 [=node], n = t&15 [=dp]) ----
        {
            int cg = node, sl = dp;
            float raw = wlds[cg * SUB + sl];
            if (cg < 12)                        // attn12 raw score rows
                ws[WS_S + ((size_t)b * 12 + cg) * NN + ch * CS + s * SUB + sl] = raw;
            float mv = raw;
            #pragma unroll
            for (int off = 1; off < 16; off <<= 1)
                mv = fmaxf(mv, __shfl_xor(mv, off, 64));
            float m_new  = fmaxf(m_run, mv);
            float sscale = __expf(m_run - m_new);
            float w      = __expf(raw - m_new);
            wlds[cg * SUB + sl] = w;
            float lv = w;
            #pragma unroll
            for (int off = 1; off < 16; off <<= 1)
                lv += __shfl_xor(lv, off, 64);
            l_run = l_run * sscale + lv;
            m_run = m_new;
            if (sl == 0) sbuf[cg] = sscale;
        }
        __syncthreads();

        // ---- pool: wave owns queries wave*4..+3, lane owns float4 of D ----
        {
            #pragma unroll
            for (int j = 0; j < 4; ++j) {
                float s0 = sbuf[wave * 4 + j];
                acc[j].x *= s0; acc[j].y *= s0; acc[j].z *= s0; acc[j].w *= s0;
            }
            const float4* xp = xg + (size_t)s * 1024 + lane;
            #pragma unroll 4
            for (int n = 0; n < SUB; ++n) {
                float4 xn = xp[(size_t)n * 64];
                #pragma unroll
                for (int j = 0; j < 4; ++j) {
                    float ev = wlds[(wave * 4 + j) * SUB + n];
                    acc[j].x += ev * xn.x; acc[j].y += ev * xn.y;
                    acc[j].z += ev * xn.z; acc[j].w += ev * xn.w;
                }
            }
        }
        __syncthreads();                        // protect wlds for next sub
    }

    // ---- outputs ----
    if (dp == 0) {                              // one lane per c (c = node)
        ws[WS_ML + (size_t)blk * 32 + node]      = m_run;
        ws[WS_ML + (size_t)blk * 32 + 16 + node] = l_run;
    }
    float4* po = (float4*)(ws + WS_PL + (size_t)blk * (CQ * 256));
    #pragma unroll
    for (int j = 0; j < 4; ++j) po[(wave * 4 + j) * 64 + lane] = acc[j];
}

// ---------------------------------------------------------------------------
// E: combine 32 chunk partials (m,l,pooled) -> pooled row; LN; MLP -> logits;
// for c<12 also writes the attn12 output row.  grid 1024, block 256.
__global__ __launch_bounds__(256) void kE(float* __restrict__ ws,
        const float* __restrict__ lnG12, const float* __restrict__ lnB12,
        const float* __restrict__ wA12,  const float* __restrict__ bA12,
        const float* __restrict__ wB12,  const float* __restrict__ bB12,
        const float* __restrict__ lnG4,  const float* __restrict__ lnB4,
        const float* __restrict__ wA4,   const float* __restrict__ bA4,
        const float* __restrict__ wB4,   const float* __restrict__ bB4,
        float* __restrict__ out) {
    int bc = blockIdx.x;
    int b = bc >> 4, c = bc & 15;
    int t = threadIdx.x, wave = t >> 6, lane = t & 63;

    __shared__ float scl[NCH];
    __shared__ float sinvl, smv;
    if (t < NCH) {                             // 32 lanes of wave 0
        float mi = ws[WS_ML + (size_t)(b * NCH + t) * 32 + c];
        float li = ws[WS_ML + (size_t)(b * NCH + t) * 32 + 16 + c];
        float m = mi;
        #pragma unroll
        for (int off = 1; off < 32; off <<= 1) m = fmaxf(m, __shfl_xor(m, off, 64));
        float e = __expf(mi - m);
        float pl = e * li;
        #pragma unroll
        for (int off = 1; off < 32; off <<= 1) pl += __shfl_xor(pl, off, 64);
        scl[t] = e;
        if (t == 0) {
            sinvl = 1.f / pl;
            smv   = m;
        }
    }
    __syncthreads();

    float v = 0.f;
    for (int i = 0; i < NCH; ++i)
        v += scl[i] * ws[WS_PL + ((size_t)(b * NCH + i) * CQ + c) * 256 + t];
    v *= sinvl;

    // attn12 output (independent of the MLP below; overlaps its latency)
    if (c < 12) {
        float m  = smv;
        float il = sinvl;
        const float4* sr = (const float4*)(ws + WS_S + ((size_t)b * 12 + c) * NN);
        float4* ar = (float4*)(out + 1024) + ((size_t)b * 12 + c) * (NN / 4);
        #pragma unroll
        for (int k = 0; k < 2; ++k) {
            float4 s4 = sr[t + k * 256];
            float4 e4;
            e4.x = __expf(s4.x - m) * il;
            e4.y = __expf(s4.y - m) * il;
            e4.z = __expf(s4.z - m) * il;
            e4.w = __expf(s4.w - m) * il;
            ar[t + k * 256] = e4;
        }
    }

    __shared__ float wr1[4], wr2[4];
    float s = v;
    #pragma unroll
    for (int off = 32; off; off >>= 1) s += __shfl_xor(s, off, 64);
    if (lane == 0) wr1[wave] = s;
    __syncthreads();
    float mu = (wr1[0] + wr1[1] + wr1[2] + wr1[3]) * (1.f / 256.f);
    float dv = v - mu;
    s = dv * dv;
    #pragma unroll
    for (int off = 32; off; off >>= 1) s += __shfl_xor(s, off, 64);
    if (lane == 0) wr2[wave] = s;
    __syncthreads();
    float var = (wr2[0] + wr2[1] + wr2[2] + wr2[3]) * (1.f / 256.f);

    bool is12 = (c < 12);
    const float* lg = is12 ? lnG12 : lnG4;
    const float* lb = is12 ? lnB12 : lnB4;
    const float* wA = is12 ? wA12  : wA4;
    const float* bA = is12 ? bA12  : bA4;
    const float* wB = is12 ? wB12  : wB4;
    const float* bB = is12 ? bB12  : bB4;

    __shared__ float ylds[256];
    __shared__ float hred[256];
    __shared__ float hlds[128];
    float y = dv * rsqrtf(var + 1e-5f) * lg[t] + lb[t];
    ylds[t] = y;
    __syncthreads();
    {
        int j = t & 127, half = t >> 7;
        float hh = 0.f;
        const float* wc = wA + (size_t)half * 128 * 128 + j;
        #pragma unroll 4
        for (int d = 0; d < 128; ++d) hh += ylds[half * 128 + d] * wc[(size_t)d * 128];
        hred[t] = hh;
    }
    __syncthreads();
    if (t < 128) hlds[t] = fmaxf(hred[t] + hred[t + 128] + bA[t], 0.f);
    __syncthreads();
    if (t < 64) {
        float pp = hlds[t] * wB[t] + hlds[t + 64] * wB[t + 64];
        #pragma unroll
        for (int off = 32; off; off >>= 1) pp += __shfl_xor(pp, off, 64);
        if (t == 0) {
            float logit = pp + bB[0];
            if (is12) out[b * 12 + c] = logit;
            else      out[768 + b * 4 + (c - 12)] = logit;
        }
    }
}

// ---------------------------------------------------------------------------
extern "C" void kernel_launch(void* const* d_in, const int* in_sizes, int n_in,
                              void* d_out, int out_size, void* d_ws, size_t ws_size,
                              hipStream_t stream) {
    const float* x     = (const float*)d_in[0];   // [131072, 256]
    const float* gq    = (const float*)d_in[2];   // [4, 256]
    const float* w1    = (const float*)d_in[3];   // [4, 256, 512]
    const float* b1    = (const float*)d_in[4];   // [4, 512]
    const float* w2    = (const float*)d_in[5];   // [4, 512, 768]
    const float* b2    = (const float*)d_in[6];   // [4, 768]
    const float* ln12g = (const float*)d_in[7];
    const float* ln12b = (const float*)d_in[8];
    const float* w12a  = (const float*)d_in[9];   // [256, 128]
    const float* b12a  = (const float*)d_in[10];
    const float* w12b  = (const float*)d_in[11];  // [128, 1]
    const float* b12b  = (const float*)d_in[12];
    const float* ln4g  = (const float*)d_in[13];
    const float* ln4b  = (const float*)d_in[14];
    const float* w4a   = (const float*)d_in[15];
    const float* b4a   = (const float*)d_in[16];
    const float* w4b   = (const float*)d_in[17];
    const float* b4b   = (const float*)d_in[18];

    float* out = (float*)d_out;               // [768 logits12][256 logits4][1572864 attn12]
    float* ws  = (float*)d_ws;

    kA1<<<64,       256, 0, stream>>>(gq, w1, b1, ws);
    kA2<<<192,      256, 0, stream>>>(w2, b2, ws);
    kF <<<BG * NCH, 256, 0, stream>>>(x, ws);
    kE <<<1024,     256, 0, stream>>>(ws,
            ln12g, ln12b, w12a, b12a, w12b, b12b,
            ln4g,  ln4b,  w4a,  b4a,  w4b,  b4b, out);
}

// Round 6
// 319.201 us; speedup vs baseline: 1.8579x; 1.0164x over previous
//
#include <hip/hip_runtime.h>
#include <math.h>

// Problem constants
#define BG   64      // graphs
#define NN   2048    // nodes per graph
#define DD   256     // hidden dim
#define CQ   16      // 12 class queries + 4 group queries fused
#define CS   64      // nodes per chunk (block)
#define NCH  32      // chunks per graph

// Workspace layout (in floats) -- 40.1 MB, identical to round-5 (passed).
static constexpr size_t WS_Q16 = 0;                                  // [16][256]
static constexpr size_t WS_H   = 4096;                               // [4][512]
static constexpr size_t WS_S   = 6144;                               // scores [64][12][2048]
static constexpr size_t WS_ML  = WS_S + (size_t)BG * 12 * NN;        // [2048][32] chunk m|l
static constexpr size_t WS_PL  = WS_ML + (size_t)BG * NCH * 32;      // pooled [2048][16][256]

// ---------------------------------------------------------------------------
// A1: h[g][j] = relu(q[g] . w1[g][:,j] + b1[g][j]); copy group queries to
// Q16 rows 12..15.  grid 64 = 4 groups x 16 j-chunks of 32, block 256.
__global__ __launch_bounds__(256) void kA1(const float* __restrict__ gq,
                                           const float* __restrict__ w1,
                                           const float* __restrict__ b1,
                                           float* __restrict__ ws) {
    int blk = blockIdx.x;
    int g   = blk >> 4;
    int jb  = (blk & 15) * 32;
    int t   = threadIdx.x;
    __shared__ float qlds[256];
    qlds[t] = gq[g * 256 + t];
    if ((blk & 15) == 0) ws[WS_Q16 + (12 + g) * 256 + t] = gq[g * 256 + t];
    __syncthreads();
    int jl = t & 31, dp = t >> 5;              // 32 j x 8 d-parts
    float acc = 0.f;
    const float* wp = w1 + ((size_t)g * 256) * 512 + jb + jl;
    #pragma unroll 8
    for (int i = 0; i < 32; ++i) {
        int d = dp * 32 + i;
        acc += qlds[d] * wp[(size_t)d * 512];
    }
    __shared__ float red[8][33];
    red[dp][jl] = acc;
    __syncthreads();
    if (dp == 0) {
        float s = 0.f;
        #pragma unroll
        for (int p = 0; p < 8; ++p) s += red[p][jl];
        s += b1[g * 512 + jb + jl];
        ws[WS_H + g * 512 + jb + jl] = fmaxf(s, 0.f);
    }
}

// A2: flat[g][k] = h[g] . w2[g][:,k] + b2[g][k] -> Q16 rows 0..11.
// grid 192 = 4 groups x 48 k-chunks of 16, block 256 (16 k x 16 d-parts).
__global__ __launch_bounds__(256) void kA2(const float* __restrict__ w2,
                                           const float* __restrict__ b2,
                                           float* __restrict__ ws) {
    int blk = blockIdx.x;
    int g   = blk / 48;
    int kb  = (blk % 48) * 16;
    int t   = threadIdx.x;
    __shared__ float hlds[512];
    hlds[t]       = ws[WS_H + g * 512 + t];
    hlds[t + 256] = ws[WS_H + g * 512 + t + 256];
    __syncthreads();
    int kl = t & 15, dp = t >> 4;              // 16 k x 16 d-parts (32 each)
    float acc = 0.f;
    const float* wp = w2 + ((size_t)g * 512) * 768 + kb + kl;
    #pragma unroll 8
    for (int i = 0; i < 32; ++i) {
        int jj = dp * 32 + i;
        acc += hlds[jj] * wp[(size_t)jj * 768];
    }
    __shared__ float red[16][17];
    red[dp][kl] = acc;
    __syncthreads();
    if (dp == 0) {
        float s = 0.f;
        #pragma unroll
        for (int p = 0; p < 16; ++p) s += red[p][kl];
        ws[WS_Q16 + g * 768 + kb + kl] = s + b2[g * 768 + kb + kl];
    }
}

// ---------------------------------------------------------------------------
// F: fused scores + chunk-softmax + chunk pooling.
// grid 2048 = (b, 64-node chunk); block 256 (4 waves).
// NO min-waves launch bound (rounds 2/3: forced register caps -> scratch
// spill catastrophe).  LDS kept to ~16.6 KB by REUSING the q-table region
// as the quarter-partial staging buffer -> up to 9 blocks/CU by LDS;
// VGPR by design ~56-72 (sc[16] + 1 float4 in flight) -> 6-8 blocks/CU.
//
// Phase 1: wave = d-quarter, lane = node.  16 float4 x-loads per thread,
//          q via wave-uniform LDS broadcast (conflict-free), sc[16] in regs.
// Stage:   barrier; quarter partials overwrite the q region: red[dq][c][n].
// Combine: 4 partials summed + scale; class rows (c<12) -> ws scores.
// Phase 2: per-c max & sumexp (16 slots x shfl), exp weights in smem[0..1023];
//          (m,l) -> ws.
// Phase 3: wave owns 4 queries x 64 nodes; lane owns float4 of D; x re-read
//          (L1/L2-hot, 16 KB/block); ev = wave-uniform broadcast; direct
//          unnormalized pooled writes (flash-combine in kE).
__global__ __launch_bounds__(256) void kF(const float* __restrict__ x,
                                          float* __restrict__ ws) {
    __shared__ float smem[4096];               // 16 KB: q table, then red/weights
    __shared__ float mbuf[16];

    int t    = threadIdx.x;
    int blk  = blockIdx.x;
    int b    = blk >> 5, ch = blk & 31;
    int gn0  = b * NN + ch * CS;               // global node base of this chunk

    // load q table [c][64 f4] (16 KB, L2/L3-hot)
    {
        const float4* qg = (const float4*)(ws + WS_Q16);
        float4* qf = (float4*)smem;
        #pragma unroll
        for (int i = 0; i < 4; ++i) qf[t + i * 256] = qg[t + i * 256];
    }
    __syncthreads();

    int lane = t & 63, wave = t >> 6;          // lane = node, wave = d-quarter

    // ---- Phase 1: quarter scores ----
    const float4* xa = (const float4*)x + (size_t)(gn0 + lane) * 64 + wave * 16;
    float sc[16];
    #pragma unroll
    for (int c = 0; c < 16; ++c) sc[c] = 0.f;

    {
        const float4* qf = (const float4*)smem + wave * 16;  // + c*64 + i
        #pragma unroll 4
        for (int i = 0; i < 16; ++i) {
            float4 xi = xa[i];
            #pragma unroll
            for (int c = 0; c < 16; ++c) {
                float4 q = qf[c * 64 + i];     // wave-uniform broadcast
                sc[c] += q.x * xi.x + q.y * xi.y + q.z * xi.z + q.w * xi.w;
            }
        }
    }
    __syncthreads();                           // all q reads done -> reuse smem

    // stage quarter partials: red[dq][c][node]
    #pragma unroll
    for (int c = 0; c < 16; ++c) smem[wave * 1024 + c * 64 + lane] = sc[c];
    __syncthreads();

    // combine quarters + scale; weights stay in smem[0..1023]; scores -> ws
    {
        float* srow = ws + WS_S + (size_t)b * 12 * NN + ch * CS;
        #pragma unroll
        for (int k = 0; k < 4; ++k) {
            int o = k * 256 + t;               // o = c*64 + node
            float s = (smem[o] + smem[o + 1024] + smem[o + 2048] + smem[o + 3072])
                      * 0.0625f;
            smem[o] = s;                       // same-index rewrite: race-free
            int c = o >> 6;
            if (c < 12) srow[(size_t)c * NN + (o & 63)] = s;
        }
    }
    __syncthreads();

    // ---- Phase 2: chunk max / sumexp per c ----
    {
        int c = t >> 4, slot = t & 15;         // 16 c x 16 slots, 4 nodes each
        float mv = -1e30f;
        #pragma unroll
        for (int k = 0; k < 4; ++k) mv = fmaxf(mv, smem[c * 64 + slot + k * 16]);
        #pragma unroll
        for (int off = 1; off < 16; off <<= 1) mv = fmaxf(mv, __shfl_xor(mv, off, 64));
        if (slot == 0) {
            mbuf[c] = mv;
            ws[WS_ML + (size_t)blk * 32 + c] = mv;
        }
    }
    __syncthreads();
    #pragma unroll
    for (int k = 0; k < 4; ++k) {
        int o = k * 256 + t;
        smem[o] = __expf(smem[o] - mbuf[o >> 6]);
    }
    __syncthreads();
    {
        int c = t >> 4, slot = t & 15;
        float lv = 0.f;
        #pragma unroll
        for (int k = 0; k < 4; ++k) lv += smem[c * 64 + slot + k * 16];
        #pragma unroll
        for (int off = 1; off < 16; off <<= 1) lv += __shfl_xor(lv, off, 64);
        if (slot == 0) ws[WS_ML + (size_t)blk * 32 + 16 + c] = lv;
    }
    // phase 3 only reads smem[0..1023] (final after the exp barrier) -- no
    // further barrier needed.

    // ---- Phase 3: pooling; wave owns 4 query rows x all 64 nodes ----
    int c0 = wave * 4;
    float4 acc[4];
    #pragma unroll
    for (int j = 0; j < 4; ++j) acc[j] = make_float4(0.f, 0.f, 0.f, 0.f);

    const float4* xq = (const float4*)x + (size_t)gn0 * 64 + lane;
    for (int nq = 0; nq < 16; ++nq) {          // node quads over 64 nodes
        float4 x0 = xq[(size_t)(nq * 4 + 0) * 64];
        float4 x1 = xq[(size_t)(nq * 4 + 1) * 64];
        float4 x2 = xq[(size_t)(nq * 4 + 2) * 64];
        float4 x3 = xq[(size_t)(nq * 4 + 3) * 64];
        #pragma unroll
        for (int j = 0; j < 4; ++j) {
            float4 ev = *(const float4*)&smem[(c0 + j) * 64 + nq * 4];
            acc[j].x += ev.x * x0.x + ev.y * x1.x + ev.z * x2.x + ev.w * x3.x;
            acc[j].y += ev.x * x0.y + ev.y * x1.y + ev.z * x2.y + ev.w * x3.y;
            acc[j].z += ev.x * x0.z + ev.y * x1.z + ev.z * x2.z + ev.w * x3.z;
            acc[j].w += ev.x * x0.w + ev.y * x1.w + ev.z * x2.w + ev.w * x3.w;
        }
    }

    float4* po = (float4*)(ws + WS_PL + (size_t)blk * (CQ * 256));
    #pragma unroll
    for (int j = 0; j < 4; ++j) po[(c0 + j) * 64 + lane] = acc[j];
}

// ---------------------------------------------------------------------------
// E: combine 32 chunk partials (m,l,pooled) -> pooled row; LN; MLP -> logits;
// for c<12 also writes the attn12 output row.  grid 1024, block 256.
__global__ __launch_bounds__(256) void kE(float* __restrict__ ws,
        const float* __restrict__ lnG12, const float* __restrict__ lnB12,
        const float* __restrict__ wA12,  const float* __restrict__ bA12,
        const float* __restrict__ wB12,  const float* __restrict__ bB12,
        const float* __restrict__ lnG4,  const float* __restrict__ lnB4,
        const float* __restrict__ wA4,   const float* __restrict__ bA4,
        const float* __restrict__ wB4,   const float* __restrict__ bB4,
        float* __restrict__ out) {
    int bc = blockIdx.x;
    int b = bc >> 4, c = bc & 15;
    int t = threadIdx.x, wave = t >> 6, lane = t & 63;

    __shared__ float scl[NCH];
    __shared__ float sinvl, smv;
    if (t < NCH) {                             // 32 lanes of wave 0
        float mi = ws[WS_ML + (size_t)(b * NCH + t) * 32 + c];
        float li = ws[WS_ML + (size_t)(b * NCH + t) * 32 + 16 + c];
        float m = mi;
        #pragma unroll
        for (int off = 1; off < 32; off <<= 1) m = fmaxf(m, __shfl_xor(m, off, 64));
        float e = __expf(mi - m);
        float pl = e * li;
        #pragma unroll
        for (int off = 1; off < 32; off <<= 1) pl += __shfl_xor(pl, off, 64);
        scl[t] = e;
        if (t == 0) {
            sinvl = 1.f / pl;
            smv   = m;
        }
    }
    __syncthreads();

    float v = 0.f;
    for (int i = 0; i < NCH; ++i)
        v += scl[i] * ws[WS_PL + ((size_t)(b * NCH + i) * CQ + c) * 256 + t];
    v *= sinvl;

    // attn12 output (independent of the MLP below; overlaps its latency)
    if (c < 12) {
        float m  = smv;
        float il = sinvl;
        const float4* sr = (const float4*)(ws + WS_S + ((size_t)b * 12 + c) * NN);
        float4* ar = (float4*)(out + 1024) + ((size_t)b * 12 + c) * (NN / 4);
        #pragma unroll
        for (int k = 0; k < 2; ++k) {
            float4 s4 = sr[t + k * 256];
            float4 e4;
            e4.x = __expf(s4.x - m) * il;
            e4.y = __expf(s4.y - m) * il;
            e4.z = __expf(s4.z - m) * il;
            e4.w = __expf(s4.w - m) * il;
            ar[t + k * 256] = e4;
        }
    }

    __shared__ float wr1[4], wr2[4];
    float s = v;
    #pragma unroll
    for (int off = 32; off; off >>= 1) s += __shfl_xor(s, off, 64);
    if (lane == 0) wr1[wave] = s;
    __syncthreads();
    float mu = (wr1[0] + wr1[1] + wr1[2] + wr1[3]) * (1.f / 256.f);
    float dv = v - mu;
    s = dv * dv;
    #pragma unroll
    for (int off = 32; off; off >>= 1) s += __shfl_xor(s, off, 64);
    if (lane == 0) wr2[wave] = s;
    __syncthreads();
    float var = (wr2[0] + wr2[1] + wr2[2] + wr2[3]) * (1.f / 256.f);

    bool is12 = (c < 12);
    const float* lg = is12 ? lnG12 : lnG4;
    const float* lb = is12 ? lnB12 : lnB4;
    const float* wA = is12 ? wA12  : wA4;
    const float* bA = is12 ? bA12  : bA4;
    const float* wB = is12 ? wB12  : wB4;
    const float* bB = is12 ? bB12  : bB4;

    __shared__ float ylds[256];
    __shared__ float hred[256];
    __shared__ float hlds[128];
    float y = dv * rsqrtf(var + 1e-5f) * lg[t] + lb[t];
    ylds[t] = y;
    __syncthreads();
    {
        int j = t & 127, half = t >> 7;
        float hh = 0.f;
        const float* wc = wA + (size_t)half * 128 * 128 + j;
        #pragma unroll 4
        for (int d = 0; d < 128; ++d) hh += ylds[half * 128 + d] * wc[(size_t)d * 128];
        hred[t] = hh;
    }
    __syncthreads();
    if (t < 128) hlds[t] = fmaxf(hred[t] + hred[t + 128] + bA[t], 0.f);
    __syncthreads();
    if (t < 64) {
        float pp = hlds[t] * wB[t] + hlds[t + 64] * wB[t + 64];
        #pragma unroll
        for (int off = 32; off; off >>= 1) pp += __shfl_xor(pp, off, 64);
        if (t == 0) {
            float logit = pp + bB[0];
            if (is12) out[b * 12 + c] = logit;
            else      out[768 + b * 4 + (c - 12)] = logit;
        }
    }
}

// ---------------------------------------------------------------------------
extern "C" void kernel_launch(void* const* d_in, const int* in_sizes, int n_in,
                              void* d_out, int out_size, void* d_ws, size_t ws_size,
                              hipStream_t stream) {
    const float* x     = (const float*)d_in[0];   // [131072, 256]
    const float* gq    = (const float*)d_in[2];   // [4, 256]
    const float* w1    = (const float*)d_in[3];   // [4, 256, 512]
    const float* b1    = (const float*)d_in[4];   // [4, 512]
    const float* w2    = (const float*)d_in[5];   // [4, 512, 768]
    const float* b2    = (const float*)d_in[6];   // [4, 768]
    const float* ln12g = (const float*)d_in[7];
    const float* ln12b = (const float*)d_in[8];
    const float* w12a  = (const float*)d_in[9];   // [256, 128]
    const float* b12a  = (const float*)d_in[10];
    const float* w12b  = (const float*)d_in[11];  // [128, 1]
    const float* b12b  = (const float*)d_in[12];
    const float* ln4g  = (const float*)d_in[13];
    const float* ln4b  = (const float*)d_in[14];
    const float* w4a   = (const float*)d_in[15];
    const float* b4a   = (const float*)d_in[16];
    const float* w4b   = (const float*)d_in[17];
    const float* b4b   = (const float*)d_in[18];

    float* out = (float*)d_out;               // [768 logits12][256 logits4][1572864 attn12]
    float* ws  = (float*)d_ws;

    kA1<<<64,       256, 0, stream>>>(gq, w1, b1, ws);
    kA2<<<192,      256, 0, stream>>>(w2, b2, ws);
    kF <<<BG * NCH, 256, 0, stream>>>(x, ws);
    kE <<<1024,     256, 0, stream>>>(ws,
            ln12g, ln12b, w12a, b12a, w12b, b12b,
            ln4g,  ln4b,  w4a,  b4a,  w4b,  b4b, out);
}

// Round 7
// 289.462 us; speedup vs baseline: 2.0488x; 1.1027x over previous
//
#include <hip/hip_runtime.h>
#include <math.h>

// Problem constants
#define BG   64      // graphs
#define NN   2048    // nodes per graph
#define DD   256     // hidden dim
#define CQ   16      // 12 class queries + 4 group queries fused
#define CS   128     // nodes per chunk
#define NCH  16      // 128-node chunks per graph

// Workspace layout (in floats) -- round-1 proven layout
static constexpr size_t WS_Q16 = 0;                                  // [16][256]
static constexpr size_t WS_H   = 4096;                               // [4][512]
static constexpr size_t WS_S   = 6144;                               // scores [64][12][2048]
static constexpr size_t WS_ML  = WS_S + (size_t)BG * 12 * NN;        // [64*16][32] chunk m|l
static constexpr size_t WS_PL  = WS_ML + (size_t)BG * NCH * 32;      // pooled [64*16][16][256]

// ---------------------------------------------------------------------------
// A1: h[g][j] = relu(q[g] . w1[g][:,j] + b1[g][j]); copy group queries to
// Q16 rows 12..15.  grid 64 = 4 groups x 16 j-chunks of 32, block 256.
__global__ __launch_bounds__(256) void kA1(const float* __restrict__ gq,
                                           const float* __restrict__ w1,
                                           const float* __restrict__ b1,
                                           float* __restrict__ ws) {
    int blk = blockIdx.x;
    int g   = blk >> 4;
    int jb  = (blk & 15) * 32;
    int t   = threadIdx.x;
    __shared__ float qlds[256];
    qlds[t] = gq[g * 256 + t];
    if ((blk & 15) == 0) ws[WS_Q16 + (12 + g) * 256 + t] = gq[g * 256 + t];
    __syncthreads();
    int jl = t & 31, dp = t >> 5;              // 32 j x 8 d-parts
    float acc = 0.f;
    const float* wp = w1 + ((size_t)g * 256) * 512 + jb + jl;
    #pragma unroll 8
    for (int i = 0; i < 32; ++i) {
        int d = dp * 32 + i;
        acc += qlds[d] * wp[(size_t)d * 512];
    }
    __shared__ float red[8][33];
    red[dp][jl] = acc;
    __syncthreads();
    if (dp == 0) {
        float s = 0.f;
        #pragma unroll
        for (int p = 0; p < 8; ++p) s += red[p][jl];
        s += b1[g * 512 + jb + jl];
        ws[WS_H + g * 512 + jb + jl] = fmaxf(s, 0.f);
    }
}

// A2: flat[g][k] = h[g] . w2[g][:,k] + b2[g][k] -> Q16 rows 0..11.
// grid 192 = 4 groups x 48 k-chunks of 16, block 256 (16 k x 16 d-parts).
__global__ __launch_bounds__(256) void kA2(const float* __restrict__ w2,
                                           const float* __restrict__ b2,
                                           float* __restrict__ ws) {
    int blk = blockIdx.x;
    int g   = blk / 48;
    int kb  = (blk % 48) * 16;
    int t   = threadIdx.x;
    __shared__ float hlds[512];
    hlds[t]       = ws[WS_H + g * 512 + t];
    hlds[t + 256] = ws[WS_H + g * 512 + t + 256];
    __syncthreads();
    int kl = t & 15, dp = t >> 4;              // 16 k x 16 d-parts (32 each)
    float acc = 0.f;
    const float* wp = w2 + ((size_t)g * 512) * 768 + kb + kl;
    #pragma unroll 8
    for (int i = 0; i < 32; ++i) {
        int jj = dp * 32 + i;
        acc += hlds[jj] * wp[(size_t)jj * 768];
    }
    __shared__ float red[16][17];
    red[dp][kl] = acc;
    __syncthreads();
    if (dp == 0) {
        float s = 0.f;
        #pragma unroll
        for (int p = 0; p < 16; ++p) s += red[p][kl];
        ws[WS_Q16 + g * 768 + kb + kl] = s + b2[g * 768 + kb + kl];
    }
}

// ---------------------------------------------------------------------------
// F: fused scores + chunk-softmax-partials + chunk pooling.
// grid 1024 = (b, chunk of 128 nodes); block 256 (4 waves).
// MEASURED OPTIMUM (round 1: 82 us, VGPR 64, no spill).  Do NOT add a
// min-waves launch bound (rounds 2/3: register cap -> scratch spill) and do
// NOT reduce per-thread ILP for occupancy (rounds 4/5/6: all slower).
// Phase 1: 2 threads per node (D split in halves), 8-deep prefetch, q16 via
//          LDS broadcast; halves combined through wlds; scaled scores kept in
//          wlds and the 12 class rows written to ws.
// Phase 2: per-c chunk max & sumexp (LDS + 16-lane shfl); exp-weights in wlds.
// Phase 3: wave = (node-half, query-half): 64 nodes x 8 queries per wave,
//          lane owns float4 of D; x re-read from global (chunk is L2-hot);
//          single-round cross-wave combine.  Emits (m,l) + pooled[16][256].
__global__ __launch_bounds__(256) void kF(const float* __restrict__ x,
                                          float* __restrict__ ws) {
    __shared__ float4 qlds[CQ * 64];           // 16 KB: q16 [c][d4]; reused as combine scratch
    __shared__ float  wlds[CQ * CS];           // 8 KB: scores then exp-weights [c][n]
    __shared__ float  mbuf[CQ], lbuf[CQ];

    int t   = threadIdx.x;
    int blk = blockIdx.x;
    int b   = blk >> 4, ch = blk & 15;
    int gn0 = b * NN + ch * CS;                // global node base of this chunk

    const float4* qg = (const float4*)(ws + WS_Q16);
    #pragma unroll
    for (int i = 0; i < 4; ++i) qlds[t + i * 256] = qg[t + i * 256];
    __syncthreads();

    // ---- Phase 1: scores; thread = (node = t&127, d-half = t>>7) ----
    int node = t & 127, half = t >> 7;
    const float4* xa = (const float4*)x + (size_t)(gn0 + node) * 64 + half * 32;
    float sc[CQ];
    #pragma unroll
    for (int c = 0; c < CQ; ++c) sc[c] = 0.f;

    float4 buf[8];
    #pragma unroll
    for (int i = 0; i < 8; ++i) buf[i] = xa[i];
    for (int base = 0; base < 32; base += 8) {
        float4 cur[8];
        #pragma unroll
        for (int i = 0; i < 8; ++i) cur[i] = buf[i];
        if (base + 8 < 32) {
            #pragma unroll
            for (int i = 0; i < 8; ++i) buf[i] = xa[base + 8 + i];
        }
        #pragma unroll
        for (int i = 0; i < 8; ++i) {
            #pragma unroll
            for (int c = 0; c < CQ; ++c) {
                float4 q = qlds[c * 64 + half * 32 + base + i];
                sc[c] += q.x * cur[i].x + q.y * cur[i].y
                       + q.z * cur[i].z + q.w * cur[i].w;
            }
        }
    }

    // combine d-halves through wlds; half0 finishes with scale
    if (half == 1) {
        #pragma unroll
        for (int c = 0; c < CQ; ++c) wlds[c * CS + node] = sc[c];
    }
    __syncthreads();
    if (half == 0) {
        #pragma unroll
        for (int c = 0; c < CQ; ++c)
            wlds[c * CS + node] = (sc[c] + wlds[c * CS + node]) * 0.0625f;
    }
    __syncthreads();

    // raw scaled scores for the 12 class queries -> ws (needed by kE's attn)
    {
        float* srow = ws + WS_S + (size_t)b * 12 * NN + ch * CS;
        #pragma unroll
        for (int k = 0; k < 6; ++k) {          // 12*128 = 1536 = 6*256
            int idx = k * 256 + t;
            srow[(size_t)(idx >> 7) * NN + (idx & 127)] = wlds[idx];
        }
    }

    // ---- Phase 2: chunk max / sumexp per c ----
    {
        int c = t >> 4, slot = t & 15;
        float mv = -1e30f;
        #pragma unroll
        for (int k = 0; k < 8; ++k) mv = fmaxf(mv, wlds[c * CS + slot + k * 16]);
        #pragma unroll
        for (int off = 1; off < 16; off <<= 1) mv = fmaxf(mv, __shfl_xor(mv, off, 64));
        if (slot == 0) mbuf[c] = mv;
    }
    __syncthreads();
    #pragma unroll
    for (int k = 0; k < 8; ++k) {              // 16*128 = 2048 = 8*256
        int idx = k * 256 + t;
        wlds[idx] = __expf(wlds[idx] - mbuf[idx >> 7]);
    }
    __syncthreads();
    {
        int c = t >> 4, slot = t & 15;
        float lv = 0.f;
        #pragma unroll
        for (int k = 0; k < 8; ++k) lv += wlds[c * CS + slot + k * 16];
        #pragma unroll
        for (int off = 1; off < 16; off <<= 1) lv += __shfl_xor(lv, off, 64);
        if (slot == 0) lbuf[c] = lv;
    }
    __syncthreads();
    if (t < CQ) {
        ws[WS_ML + (size_t)blk * 32 + t]      = mbuf[t];
        ws[WS_ML + (size_t)blk * 32 + 16 + t] = lbuf[t];
    }

    // ---- Phase 3: pooling; wave = (ng = node-half, cg = query-half) ----
    int wave = t >> 6, lane = t & 63;
    int ng = wave & 1, cg = wave >> 1;         // 64 nodes x 8 queries per wave
    float4 acc[8];
    #pragma unroll
    for (int j = 0; j < 8; ++j) acc[j] = make_float4(0.f, 0.f, 0.f, 0.f);

    const float4* xq = (const float4*)x + (size_t)(gn0 + ng * 64) * 64 + lane;
    for (int nq = 0; nq < 16; ++nq) {          // node quads
        float4 x0 = xq[(size_t)(nq * 4 + 0) * 64];
        float4 x1 = xq[(size_t)(nq * 4 + 1) * 64];
        float4 x2 = xq[(size_t)(nq * 4 + 2) * 64];
        float4 x3 = xq[(size_t)(nq * 4 + 3) * 64];
        #pragma unroll
        for (int j = 0; j < 8; ++j) {
            int c = cg * 8 + j;
            float4 ev = *(const float4*)&wlds[c * CS + ng * 64 + nq * 4];
            acc[j].x += ev.x * x0.x + ev.y * x1.x + ev.z * x2.x + ev.w * x3.x;
            acc[j].y += ev.x * x0.y + ev.y * x1.y + ev.z * x2.y + ev.w * x3.y;
            acc[j].z += ev.x * x0.z + ev.y * x1.z + ev.z * x2.z + ev.w * x3.z;
            acc[j].w += ev.x * x0.w + ev.y * x1.w + ev.z * x2.w + ev.w * x3.w;
        }
    }

    // single-round cross-wave combine; qlds no longer needed -> scratch
    float4* sdata = qlds;                      // [16][64] float4 = [16][256] float
    if (ng == 0) {
        #pragma unroll
        for (int j = 0; j < 8; ++j) sdata[(cg * 8 + j) * 64 + lane] = acc[j];
    }
    __syncthreads();
    if (ng == 1) {
        #pragma unroll
        for (int j = 0; j < 8; ++j) {
            float4* p = &sdata[(cg * 8 + j) * 64 + lane];
            float4 v = *p;
            v.x += acc[j].x; v.y += acc[j].y; v.z += acc[j].z; v.w += acc[j].w;
            *p = v;
        }
    }
    __syncthreads();
    float* po = ws + WS_PL + (size_t)blk * (CQ * 256);
    const float* sf = (const float*)sdata;
    #pragma unroll
    for (int i = 0; i < CQ; ++i) po[t + i * 256] = sf[t + i * 256];
}

// ---------------------------------------------------------------------------
// E: combine 16 chunk partials (m,l,pooled) -> pooled row; LN; MLP -> logits;
// for c<12 also writes the attn12 output row.  grid 1024, block 256.
__global__ __launch_bounds__(256) void kE(float* __restrict__ ws,
        const float* __restrict__ lnG12, const float* __restrict__ lnB12,
        const float* __restrict__ wA12,  const float* __restrict__ bA12,
        const float* __restrict__ wB12,  const float* __restrict__ bB12,
        const float* __restrict__ lnG4,  const float* __restrict__ lnB4,
        const float* __restrict__ wA4,   const float* __restrict__ bA4,
        const float* __restrict__ wB4,   const float* __restrict__ bB4,
        float* __restrict__ out) {
    int bc = blockIdx.x;
    int b = bc >> 4, c = bc & 15;
    int t = threadIdx.x, wave = t >> 6, lane = t & 63;

    __shared__ float scl[NCH];
    __shared__ float sinvl, smv;
    if (t < NCH) {                             // 16 lanes of wave 0
        float mi = ws[WS_ML + (size_t)(b * NCH + t) * 32 + c];
        float li = ws[WS_ML + (size_t)(b * NCH + t) * 32 + 16 + c];
        float m = mi;
        #pragma unroll
        for (int off = 1; off < 16; off <<= 1) m = fmaxf(m, __shfl_xor(m, off, 64));
        float e = __expf(mi - m);
        float pl = e * li;
        #pragma unroll
        for (int off = 1; off < 16; off <<= 1) pl += __shfl_xor(pl, off, 64);
        scl[t] = e;
        if (t == 0) {
            sinvl = 1.f / pl;
            smv   = m;
        }
    }
    __syncthreads();

    float v = 0.f;
    for (int i = 0; i < NCH; ++i)
        v += scl[i] * ws[WS_PL + ((size_t)(b * NCH + i) * CQ + c) * 256 + t];
    v *= sinvl;

    // attn12 output (independent of the MLP below; overlaps its latency)
    if (c < 12) {
        float m  = smv;
        float il = sinvl;
        const float4* sr = (const float4*)(ws + WS_S + ((size_t)b * 12 + c) * NN);
        float4* ar = (float4*)(out + 1024) + ((size_t)b * 12 + c) * (NN / 4);
        #pragma unroll
        for (int k = 0; k < 2; ++k) {
            float4 s4 = sr[t + k * 256];
            float4 e4;
            e4.x = __expf(s4.x - m) * il;
            e4.y = __expf(s4.y - m) * il;
            e4.z = __expf(s4.z - m) * il;
            e4.w = __expf(s4.w - m) * il;
            ar[t + k * 256] = e4;
        }
    }

    __shared__ float wr1[4], wr2[4];
    float s = v;
    #pragma unroll
    for (int off = 32; off; off >>= 1) s += __shfl_xor(s, off, 64);
    if (lane == 0) wr1[wave] = s;
    __syncthreads();
    float mu = (wr1[0] + wr1[1] + wr1[2] + wr1[3]) * (1.f / 256.f);
    float dv = v - mu;
    s = dv * dv;
    #pragma unroll
    for (int off = 32; off; off >>= 1) s += __shfl_xor(s, off, 64);
    if (lane == 0) wr2[wave] = s;
    __syncthreads();
    float var = (wr2[0] + wr2[1] + wr2[2] + wr2[3]) * (1.f / 256.f);

    bool is12 = (c < 12);
    const float* lg = is12 ? lnG12 : lnG4;
    const float* lb = is12 ? lnB12 : lnB4;
    const float* wA = is12 ? wA12  : wA4;
    const float* bA = is12 ? bA12  : bA4;
    const float* wB = is12 ? wB12  : wB4;
    const float* bB = is12 ? bB12  : bB4;

    __shared__ float ylds[256];
    __shared__ float hred[256];
    __shared__ float hlds[128];
    float y = dv * rsqrtf(var + 1e-5f) * lg[t] + lb[t];
    ylds[t] = y;
    __syncthreads();
    {
        int j = t & 127, half = t >> 7;
        float hh = 0.f;
        const float* wc = wA + (size_t)half * 128 * 128 + j;
        #pragma unroll 4
        for (int d = 0; d < 128; ++d) hh += ylds[half * 128 + d] * wc[(size_t)d * 128];
        hred[t] = hh;
    }
    __syncthreads();
    if (t < 128) hlds[t] = fmaxf(hred[t] + hred[t + 128] + bA[t], 0.f);
    __syncthreads();
    if (t < 64) {
        float pp = hlds[t] * wB[t] + hlds[t + 64] * wB[t + 64];
        #pragma unroll
        for (int off = 32; off; off >>= 1) pp += __shfl_xor(pp, off, 64);
        if (t == 0) {
            float logit = pp + bB[0];
            if (is12) out[b * 12 + c] = logit;
            else      out[768 + b * 4 + (c - 12)] = logit;
        }
    }
}

// ---------------------------------------------------------------------------
extern "C" void kernel_launch(void* const* d_in, const int* in_sizes, int n_in,
                              void* d_out, int out_size, void* d_ws, size_t ws_size,
                              hipStream_t stream) {
    const float* x     = (const float*)d_in[0];   // [131072, 256]
    const float* gq    = (const float*)d_in[2];   // [4, 256]
    const float* w1    = (const float*)d_in[3];   // [4, 256, 512]
    const float* b1    = (const float*)d_in[4];   // [4, 512]
    const float* w2    = (const float*)d_in[5];   // [4, 512, 768]
    const float* b2    = (const float*)d_in[6];   // [4, 768]
    const float* ln12g = (const float*)d_in[7];
    const float* ln12b = (const float*)d_in[8];
    const float* w12a  = (const float*)d_in[9];   // [256, 128]
    const float* b12a  = (const float*)d_in[10];
    const float* w12b  = (const float*)d_in[11];  // [128, 1]
    const float* b12b  = (const float*)d_in[12];
    const float* ln4g  = (const float*)d_in[13];
    const float* ln4b  = (const float*)d_in[14];
    const float* w4a   = (const float*)d_in[15];
    const float* b4a   = (const float*)d_in[16];
    const float* w4b   = (const float*)d_in[17];
    const float* b4b   = (const float*)d_in[18];

    float* out = (float*)d_out;               // [768 logits12][256 logits4][1572864 attn12]
    float* ws  = (float*)d_ws;

    kA1<<<64,       256, 0, stream>>>(gq, w1, b1, ws);
    kA2<<<192,      256, 0, stream>>>(w2, b2, ws);
    kF <<<BG * NCH, 256, 0, stream>>>(x, ws);
    kE <<<1024,     256, 0, stream>>>(ws,
            ln12g, ln12b, w12a, b12a, w12b, b12b,
            ln4g,  ln4b,  w4a,  b4a,  w4b,  b4b, out);
}